// Round 4
// baseline (1189.971 us; speedup 1.0000x reference)
//
#include <hip/hip_runtime.h>

namespace {

constexpr int kN = 50000, kE = 200000, kG = 500;
constexpr float kEps = 1e-5f;
constexpr int kBlocks = 256, kThreads = 1024;
constexpr int kTileN = 256;                           // nodes per MFMA tile
constexpr int kTiles = (kN + kTileN - 1) / kTileN;    // 196

typedef short v8s __attribute__((ext_vector_type(8)));
typedef float v4f __attribute__((ext_vector_type(4)));

__device__ __forceinline__ unsigned short bf16rn(float x) {
    unsigned u = __float_as_uint(x);
    return (unsigned short)((u + 0x7FFFu + ((u >> 16) & 1u)) >> 16);
}
__device__ __forceinline__ float bf16lo(unsigned p) { return __uint_as_float(p << 16); }
__device__ __forceinline__ float bf16hi(unsigned p) { return __uint_as_float(p & 0xFFFF0000u); }

struct SMem {
    union {
        struct { unsigned short sx[kTileN * 96]; unsigned short sW[32 * 96]; } init;
        float sW1[256];
        struct { unsigned short sh[kTileN * 32]; unsigned short sB[224 * 32]; } yr;
        struct { float ls[1024]; float lq[1024]; } red;
        float seg[kG];
    };
};

__global__ void ws_init(unsigned* barCnt, float* stats) {
    if (threadIdx.x == 0) *barCnt = 0u;
    if (threadIdx.x < 64) stats[threadIdx.x] = 0.f;
}

__global__ __launch_bounds__(kThreads) void gnn_persist(
    const float* __restrict__ x, const int* __restrict__ ei,
    const float* __restrict__ ea, const int* __restrict__ batch,
    const float* __restrict__ lin_W, const float* __restrict__ lin_b,
    const float* __restrict__ mes_W1, const float* __restrict__ mes_b1,
    const float* __restrict__ mes_W2, const float* __restrict__ mes_b2,
    const float* __restrict__ root_W, const float* __restrict__ conv_b,
    const float* __restrict__ bn_g, const float* __restrict__ bn_b,
    const float* __restrict__ pred_W, const float* __restrict__ pred_b,
    float* __restrict__ out,
    unsigned* __restrict__ barCnt, float* __restrict__ stats,
    float* __restrict__ hbuf, float* __restrict__ obuf,
    unsigned short* __restrict__ Yus, unsigned* __restrict__ hidpk,
    float* __restrict__ vbuf)
{
    __shared__ SMem sm;
    const int t = threadIdx.x;
    const int bid = blockIdx.x;
    const int l15 = t & 15, quad = (t >> 4) & 3, w = t >> 6;  // wave 0..15
    unsigned target = 0;

    auto gsync = [&]() {
        __syncthreads();
        target += kBlocks;
        if (t == 0) {
            __threadfence();                       // release: write back L2
            atomicAdd(barCnt, 1u);
            while (atomicAdd(barCnt, 0u) < target) __builtin_amdgcn_s_sleep(2);
        }
        __syncthreads();
        __threadfence();                           // acquire: invalidate L1/L2
    };

    // ---------------- P0: init h = leaky(x @ lin_W + lin_b) via MFMA -------
    for (int i = t; i < kTileN * 96; i += kThreads) sm.init.sx[i] = 0;
    for (int i = t; i < 32 * 96; i += kThreads) sm.init.sW[i] = 0;
    __syncthreads();
    if (bid < kTiles) {
        int tb = bid * kTileN;
        int cnt = min(kTileN, kN - tb);
        for (int i = t; i < cnt * 75; i += kThreads) {
            float v = x[(size_t)tb * 75 + i];
            int n = i / 75;
            int f = i - n * 75;
            sm.init.sx[n * 96 + f] = bf16rn(v);
        }
    }
    for (int i = t; i < 75 * 32; i += kThreads) {
        int f = i >> 5, c = i & 31;
        sm.init.sW[c * 96 + f] = bf16rn(lin_W[i]);
    }
    __syncthreads();
    if (bid < kTiles) {
        int tb = bid * kTileN;
        v4f acc0 = {0.f, 0.f, 0.f, 0.f}, acc1 = {0.f, 0.f, 0.f, 0.f};
        #pragma unroll
        for (int kc = 0; kc < 3; ++kc) {
            v8s a  = *(const v8s*)&sm.init.sx[(w * 16 + l15) * 96 + kc * 32 + quad * 8];
            v8s b0 = *(const v8s*)&sm.init.sW[l15 * 96 + kc * 32 + quad * 8];
            v8s b1 = *(const v8s*)&sm.init.sW[(16 + l15) * 96 + kc * 32 + quad * 8];
            acc0 = __builtin_amdgcn_mfma_f32_16x16x32_bf16(a, b0, acc0, 0, 0, 0);
            acc1 = __builtin_amdgcn_mfma_f32_16x16x32_bf16(a, b1, acc1, 0, 0, 0);
        }
        float bl0 = lin_b[l15], bl1 = lin_b[16 + l15];
        #pragma unroll
        for (int r = 0; r < 4; ++r) {
            int n = tb + w * 16 + quad * 4 + r;
            if (n < kN) {
                float v0 = acc0[r] + bl0, v1 = acc1[r] + bl1;
                hbuf[n * 32 + l15]      = v0 > 0.f ? v0 : 0.01f * v0;
                hbuf[n * 32 + 16 + l15] = v1 > 0.f ? v1 : 0.01f * v1;
            }
        }
    }
    __syncthreads();

    // ---------------- P0b: hid = relu(ea@W1+b1) for all 3 layers -----------
    for (int i = t; i < 195; i += kThreads)
        sm.sW1[i] = (i < 180) ? mes_W1[i] : mes_b1[i - 180];
    __syncthreads();
    for (int e = bid * kThreads + t; e < kE; e += kBlocks * kThreads) {
        float ef[12];
        #pragma unroll
        for (int j = 0; j < 12; ++j) ef[j] = ea[(size_t)e * 12 + j];
        #pragma unroll
        for (int l = 0; l < 3; ++l) {
            float h[5];
            #pragma unroll
            for (int k = 0; k < 5; ++k) h[k] = sm.sW1[180 + l * 5 + k];
            #pragma unroll
            for (int f = 0; f < 12; ++f)
                #pragma unroll
                for (int k = 0; k < 5; ++k)
                    h[k] = fmaf(ef[f], sm.sW1[l * 60 + f * 5 + k], h[k]);
            #pragma unroll
            for (int k = 0; k < 5; ++k) h[k] = h[k] > 0.f ? h[k] : 0.f;
            size_t o = ((size_t)l * kE + e) * 3;
            hidpk[o + 0] = (unsigned)bf16rn(h[0]) | ((unsigned)bf16rn(h[1]) << 16);
            hidpk[o + 1] = (unsigned)bf16rn(h[2]) | ((unsigned)bf16rn(h[3]) << 16);
            hidpk[o + 2] = (unsigned)bf16rn(h[4]);
        }
    }
    gsync();

    // ---------------- layer loop ------------------------------------------
    for (int l = 0; l < 3; ++l) {
        // --- P1: Y + root via MFMA:  [256,32] @ [32,224]  (BN of prev fused)
        const float* W2 = mes_W2 + (size_t)l * 5120;
        const float* b2 = mes_b2 + (size_t)l * 1024;
        const float* rW = root_W + (size_t)l * 1024;
        for (int i = t; i < 7168; i += kThreads) {
            int k = i >> 10, r = i & 1023, c = r >> 5, d = r & 31;
            float v = (k < 5) ? W2[i] : (k == 5 ? b2[r] : rW[r]);
            sm.yr.sB[(k * 32 + d) * 32 + c] = bf16rn(v);
        }
        if (bid < kTiles) {
            int tb = bid * kTileN;
            int cnt = min(kTileN, kN - tb);
            int c = t & 31;
            float mu = 0.f, inv = 1.f, bb = 0.f;
            if (l > 0) {
                mu = stats[c] * (1.f / kN);
                float var = stats[32 + c] * (1.f / kN) - mu * mu;
                inv = rsqrtf(var + kEps) * bn_g[(l - 1) * 32 + c];
                bb = bn_b[(l - 1) * 32 + c];
            }
            #pragma unroll
            for (int j = 0; j < 8; ++j) {
                int idx = t + j * kThreads;
                int nl = idx >> 5;
                float v = 0.f;
                if (nl < cnt) {
                    if (l == 0) v = hbuf[(size_t)(tb + nl) * 32 + c];
                    else {
                        float o = obuf[(size_t)(tb + nl) * 32 + c];
                        v = (o - mu) * inv + bb;
                        v = v > 0.f ? v : 0.01f * v;
                    }
                }
                sm.yr.sh[idx] = bf16rn(v);
            }
        }
        __syncthreads();
        if (bid < kTiles) {
            int tb = bid * kTileN;
            v8s a = *(const v8s*)&sm.yr.sh[(w * 16 + l15) * 32 + quad * 8];
            #pragma unroll
            for (int nt = 0; nt < 14; ++nt) {
                v8s b = *(const v8s*)&sm.yr.sB[(nt * 16 + l15) * 32 + quad * 8];
                v4f dacc = {0.f, 0.f, 0.f, 0.f};
                dacc = __builtin_amdgcn_mfma_f32_16x16x32_bf16(a, b, dacc, 0, 0, 0);
                int outc = nt * 16 + l15;
                int k = outc >> 5, d = outc & 31;
                if (k < 6) {
                    #pragma unroll
                    for (int r = 0; r < 4; ++r) {
                        int n = tb + w * 16 + quad * 4 + r;
                        if (n < kN) Yus[(size_t)n * 192 + d * 6 + k] = bf16rn(dacc[r]);
                    }
                } else {
                    float cbv = conv_b[l * 32 + d];
                    #pragma unroll
                    for (int r = 0; r < 4; ++r) {
                        int n = tb + w * 16 + quad * 4 + r;
                        if (n < kN) obuf[(size_t)n * 32 + d] = dacc[r] + cbv;
                    }
                }
            }
        }
        gsync();

        // --- P2: edge scatter: msg = Y5 + sum_k hid_k*Yk, atomic into obuf
        if (bid == 0 && t < 64) stats[t] = 0.f;   // reset BN stats for this layer
        {
            const unsigned* hp = hidpk + (size_t)l * kE * 3;
            const unsigned* Ydw = (const unsigned*)Yus;
            int g = bid * 32 + (t >> 5);
            int d = t & 31;
            #pragma unroll 2
            for (int e = g; e < kE; e += kBlocks * 32) {
                int src = ei[e];
                int dst = ei[kE + e];
                unsigned q0 = hp[(size_t)e * 3 + 0];
                unsigned q1 = hp[(size_t)e * 3 + 1];
                unsigned q2 = hp[(size_t)e * 3 + 2];
                const unsigned* yr = Ydw + (size_t)src * 96 + d * 3;
                unsigned p0 = yr[0], p1 = yr[1], p2 = yr[2];
                float m = bf16hi(p2);
                m = fmaf(bf16lo(q0), bf16lo(p0), m);
                m = fmaf(bf16hi(q0), bf16hi(p0), m);
                m = fmaf(bf16lo(q1), bf16lo(p1), m);
                m = fmaf(bf16hi(q1), bf16hi(p1), m);
                m = fmaf(bf16lo(q2), bf16lo(p2), m);
                atomicAdd(&obuf[(size_t)dst * 32 + d], m);
            }
        }
        gsync();

        // --- P3: BN stats reduce
        {
            int c = t & 31, row = t >> 5;
            float s = 0.f, q = 0.f;
            for (int n = bid * 32 + row; n < kN; n += kBlocks * 32) {
                float v = obuf[(size_t)n * 32 + c];
                s += v; q += v * v;
            }
            sm.red.ls[t] = s; sm.red.lq[t] = q;
            __syncthreads();
            #pragma unroll
            for (int off = 512; off >= 32; off >>= 1) {
                if (t < off) { sm.red.ls[t] += sm.red.ls[t + off]; sm.red.lq[t] += sm.red.lq[t + off]; }
                __syncthreads();
            }
            if (t < 32) {
                atomicAdd(&stats[t], sm.red.ls[t]);
                atomicAdd(&stats[32 + t], sm.red.lq[t]);
            }
        }
        gsync();
    }

    // ---------------- P4: final BN + prediction dot -> vbuf ----------------
    {
        int c = t & 31;
        float mu = stats[c] * (1.f / kN);
        float var = stats[32 + c] * (1.f / kN) - mu * mu;
        float inv = rsqrtf(var + kEps);
        float gg = bn_g[64 + c], bb = bn_b[64 + c], pw = pred_W[c];
        if (bid == 0 && t < kG) out[t] = pred_b[0];
        for (int i = bid * kThreads + t; i < kN * 32; i += kBlocks * kThreads) {
            int n = i >> 5;
            float v = (obuf[i] - mu) * inv * gg + bb;
            float pv = v * pw;
            #pragma unroll
            for (int off = 16; off > 0; off >>= 1) pv += __shfl_down(pv, off, 32);
            if (c == 0) vbuf[n] = pv;
        }
    }
    gsync();

    // ---------------- P5: segment readout (sorted batch) -------------------
    {
        for (int i = t; i < kG; i += kThreads) sm.seg[i] = 0.f;
        __syncthreads();
        int base = (bid * kThreads + t) * 8;
        if (base < kN) {
            int cur = -1; float acc = 0.f;
            #pragma unroll
            for (int ii = 0; ii < 8; ++ii) {
                int n = base + ii;
                if (n >= kN) break;
                int gi = batch[n];
                float val = vbuf[n];
                if (gi != cur) {
                    if (cur >= 0) atomicAdd(&sm.seg[cur], acc);
                    cur = gi; acc = val;
                } else acc += val;
            }
            if (cur >= 0) atomicAdd(&sm.seg[cur], acc);
        }
        __syncthreads();
        for (int i = t; i < kG; i += kThreads) {
            float s = sm.seg[i];
            if (s != 0.f) atomicAdd(&out[i], s);
        }
    }
}

} // namespace

extern "C" void kernel_launch(void* const* d_in, const int* in_sizes, int n_in,
                              void* d_out, int out_size, void* d_ws, size_t ws_size,
                              hipStream_t stream)
{
    const float* x      = (const float*)d_in[0];
    const int*   ei     = (const int*)d_in[1];
    const float* ea     = (const float*)d_in[2];
    const int*   batch  = (const int*)d_in[3];
    const float* lin_W  = (const float*)d_in[4];
    const float* lin_b  = (const float*)d_in[5];
    const float* mes_W1 = (const float*)d_in[6];
    const float* mes_b1 = (const float*)d_in[7];
    const float* mes_W2 = (const float*)d_in[8];
    const float* mes_b2 = (const float*)d_in[9];
    const float* root_W = (const float*)d_in[10];
    const float* conv_b = (const float*)d_in[11];
    const float* bn_g   = (const float*)d_in[12];
    const float* bn_b   = (const float*)d_in[13];
    const float* pred_W = (const float*)d_in[14];
    const float* pred_b = (const float*)d_in[15];
    float* out = (float*)d_out;

    // workspace: barCnt | stats[64] | hbuf | obuf | Y(bf16) | hidpk | vbuf
    char* wsb = (char*)d_ws;
    unsigned* barCnt = (unsigned*)wsb;
    float* stats = (float*)(wsb + 256);
    float* hbuf = (float*)(wsb + 512);
    float* obuf = hbuf + (size_t)kN * 32;
    unsigned short* Yus = (unsigned short*)(obuf + (size_t)kN * 32);
    unsigned* hidpk = (unsigned*)(Yus + (size_t)kN * 192);
    float* vbuf = (float*)(hidpk + (size_t)3 * kE * 3);

    ws_init<<<1, 64, 0, stream>>>(barCnt, stats);
    gnn_persist<<<kBlocks, kThreads, 0, stream>>>(
        x, ei, ea, batch, lin_W, lin_b, mes_W1, mes_b1, mes_W2, mes_b2,
        root_W, conv_b, bn_g, bn_b, pred_W, pred_b, out,
        barCnt, stats, hbuf, obuf, Yus, hidpk, vbuf);
}

// Round 5
// 310.215 us; speedup vs baseline: 3.8360x; 3.8360x over previous
//
#include <hip/hip_runtime.h>

namespace {

constexpr int kN = 50000, kE = 200000, kG = 500;
constexpr float kEps = 1e-5f;

typedef short v8s __attribute__((ext_vector_type(8)));
typedef float v4f __attribute__((ext_vector_type(4)));

__device__ __forceinline__ unsigned short bf16rn(float x) {
    unsigned u = __float_as_uint(x);
    return (unsigned short)((u + 0x7FFFu + ((u >> 16) & 1u)) >> 16);
}
__device__ __forceinline__ float bf16lo(unsigned p) { return __uint_as_float(p << 16); }
__device__ __forceinline__ float bf16hi(unsigned p) { return __uint_as_float(p & 0xFFFF0000u); }
__device__ __forceinline__ unsigned pk2(float a, float b) {
    return (unsigned)bf16rn(a) | ((unsigned)bf16rn(b) << 16);
}

// ---- init: h16 = leaky(x @ lin_W + lin_b), bf16 [n][c]. MFMA, A=weights. ----
__global__ __launch_bounds__(1024) void init_h(
    const float* __restrict__ x, const float* __restrict__ W,
    const float* __restrict__ b, unsigned short* __restrict__ h16)
{
    __shared__ unsigned short sx[256 * 96];   // [node][feat pad 96]
    __shared__ unsigned short sW[32 * 96];    // [c][feat pad 96]
    int t = threadIdx.x;
    for (int i = t; i < 256 * 96; i += 1024) sx[i] = 0;
    for (int i = t; i < 32 * 96; i += 1024) sW[i] = 0;
    __syncthreads();
    int tb = blockIdx.x * 256;
    int cnt = min(256, kN - tb);
    for (int i = t; i < cnt * 75; i += 1024) {
        int n = i / 75, f = i - n * 75;
        sx[n * 96 + f] = bf16rn(x[(size_t)tb * 75 + i]);
    }
    for (int i = t; i < 75 * 32; i += 1024) {
        int f = i >> 5, c = i & 31;
        sW[c * 96 + f] = bf16rn(W[i]);
    }
    __syncthreads();
    int l15 = t & 15, quad = (t >> 4) & 3, w = t >> 6;
    int n = tb + w * 16 + l15;
    unsigned* H = (unsigned*)h16;
    #pragma unroll
    for (int tile = 0; tile < 2; ++tile) {
        v4f acc = {0.f, 0.f, 0.f, 0.f};
        #pragma unroll
        for (int kc = 0; kc < 3; ++kc) {
            v8s a  = *(const v8s*)&sW[(tile * 16 + l15) * 96 + kc * 32 + quad * 8];
            v8s bb = *(const v8s*)&sx[(w * 16 + l15) * 96 + kc * 32 + quad * 8];
            acc = __builtin_amdgcn_mfma_f32_16x16x32_bf16(a, bb, acc, 0, 0, 0);
        }
        if (n < kN) {
            int c0 = tile * 16 + quad * 4;   // 4 consecutive output channels
            float v0 = acc[0] + b[c0],     v1 = acc[1] + b[c0 + 1];
            float v2 = acc[2] + b[c0 + 2], v3 = acc[3] + b[c0 + 3];
            v0 = v0 > 0.f ? v0 : 0.01f * v0;  v1 = v1 > 0.f ? v1 : 0.01f * v1;
            v2 = v2 > 0.f ? v2 : 0.01f * v2;  v3 = v3 > 0.f ? v3 : 0.01f * v3;
            H[n * 16 + (c0 >> 1)]     = pk2(v0, v1);
            H[n * 16 + (c0 >> 1) + 1] = pk2(v2, v3);
        }
    }
}

// ---- hid = relu(ea@W1+b1) for all 3 layers, packed 3 dwords bf16/edge. ----
__global__ __launch_bounds__(256) void hid_pre(
    const float* __restrict__ ea, const float* __restrict__ W1,
    const float* __restrict__ b1, unsigned* __restrict__ hidpk)
{
    __shared__ float sE[256 * 13];   // stride 13: conflict-free
    __shared__ float sW[195];
    int t = threadIdx.x;
    for (int i = t; i < 195; i += 256) sW[i] = (i < 180) ? W1[i] : b1[i - 180];
    int base = blockIdx.x * 256;
    int cnt = min(256, kE - base);
    for (int i = t; i < cnt * 12; i += 256) {
        int el = i / 12, f = i - el * 12;
        sE[el * 13 + f] = ea[(size_t)base * 12 + i];
    }
    __syncthreads();
    if (t >= cnt) return;
    int e = base + t;
    float ef[12];
    #pragma unroll
    for (int j = 0; j < 12; ++j) ef[j] = sE[t * 13 + j];
    #pragma unroll
    for (int l = 0; l < 3; ++l) {
        float h[5];
        #pragma unroll
        for (int k = 0; k < 5; ++k) h[k] = sW[180 + l * 5 + k];
        #pragma unroll
        for (int f = 0; f < 12; ++f)
            #pragma unroll
            for (int k = 0; k < 5; ++k)
                h[k] = fmaf(ef[f], sW[l * 60 + f * 5 + k], h[k]);
        #pragma unroll
        for (int k = 0; k < 5; ++k) h[k] = h[k] > 0.f ? h[k] : 0.f;
        size_t o = ((size_t)l * kE + e) * 3;
        hidpk[o + 0] = pk2(h[0], h[1]);
        hidpk[o + 1] = pk2(h[2], h[3]);
        hidpk[o + 2] = pk2(h[4], 0.f);
    }
}

// ---- y_root: [256 nodes,32] @ [32, 256cols(d*8+k)] via MFMA, A=weights. ----
// k=0..4 -> h@M_k, k=5 -> h@B2mat (into Y bf16 [n][d][k0..7]),
// k=6 -> h@rootW + conv_b (into obuf fp32), k=7 pad. BN of prev layer fused
// into the h staging.
__global__ __launch_bounds__(1024) void y_root(
    const unsigned short* __restrict__ h16, float* __restrict__ obuf,
    const float* __restrict__ W2, const float* __restrict__ b2,
    const float* __restrict__ rW, const float* __restrict__ convb,
    const float* __restrict__ stats,
    const float* __restrict__ gPrev, const float* __restrict__ bPrev,
    int first, unsigned short* __restrict__ Yus)
{
    __shared__ unsigned short sh[256 * 32];   // [node][c]
    __shared__ unsigned short sB[256 * 32];   // [c_out][c]
    int t = threadIdx.x;
    int tb = blockIdx.x * 256;
    int cnt = min(256, kN - tb);
    for (int i = t; i < 8192; i += 1024) {
        int co = i >> 5, c = i & 31, d = co >> 3, k = co & 7;
        float v = (k < 5) ? W2[k * 1024 + c * 32 + d]
                : (k == 5) ? b2[c * 32 + d]
                : (k == 6) ? rW[c * 32 + d] : 0.f;
        sB[co * 32 + c] = bf16rn(v);
    }
    if (first) {
        #pragma unroll
        for (int j = 0; j < 8; ++j) {
            int idx = t + j * 1024;
            int nl = idx >> 5, c = idx & 31;
            sh[idx] = (nl < cnt) ? h16[(size_t)(tb + nl) * 32 + c] : (unsigned short)0;
        }
    } else {
        int c = t & 31;
        float mu = stats[c] * (1.f / kN);
        float var = stats[32 + c] * (1.f / kN) - mu * mu;
        float ivg = rsqrtf(var + kEps) * gPrev[c];
        float bb = bPrev[c];
        #pragma unroll
        for (int j = 0; j < 8; ++j) {
            int idx = t + j * 1024;
            int nl = idx >> 5;
            float v = 0.f;
            if (nl < cnt) {
                float o = obuf[(size_t)(tb + nl) * 32 + c];
                v = (o - mu) * ivg + bb;
                v = v > 0.f ? v : 0.01f * v;
            }
            sh[idx] = bf16rn(v);
        }
    }
    __syncthreads();
    int l15 = t & 15, quad = (t >> 4) & 3, w = t >> 6;
    int n = tb + w * 16 + l15;
    v8s bn_ = *(const v8s*)&sh[(w * 16 + l15) * 32 + quad * 8];
    unsigned* Ydw = (unsigned*)Yus;
    #pragma unroll
    for (int i = 0; i < 16; ++i) {
        v8s a = *(const v8s*)&sB[(i * 16 + l15) * 32 + quad * 8];
        v4f acc = {0.f, 0.f, 0.f, 0.f};
        acc = __builtin_amdgcn_mfma_f32_16x16x32_bf16(a, bn_, acc, 0, 0, 0);
        if (n < kN) {
            int cb = i * 16 + quad * 4;
            int d = cb >> 3, koff = cb & 7;
            if (koff == 0) {
                Ydw[(size_t)n * 128 + d * 4]     = pk2(acc[0], acc[1]);  // k0,k1
                Ydw[(size_t)n * 128 + d * 4 + 1] = pk2(acc[2], acc[3]);  // k2,k3
            } else {
                Ydw[(size_t)n * 128 + d * 4 + 2] = pk2(acc[0], acc[1]);  // k4,k5
                obuf[(size_t)n * 32 + d] = acc[2] + convb[d];            // k6 root
            }
        }
    }
}

// ---- edge scatter: msg = Y5 + sum_k hid_k*Yk, atomicAdd into obuf[dst]. ----
__global__ __launch_bounds__(256) void edge_msg(
    const int* __restrict__ ei, const unsigned* __restrict__ hp,
    const unsigned short* __restrict__ Yus, float* __restrict__ obuf,
    float* __restrict__ stats)
{
    int t = threadIdx.x;
    if (blockIdx.x == 0 && t < 64) stats[t] = 0.f;   // reset BN stats this layer
    int gid = blockIdx.x * 256 + t;
    int e = gid >> 5, d = gid & 31;
    int src = ei[e];
    int dst = ei[kE + e];
    unsigned q0 = hp[(size_t)e * 3 + 0];
    unsigned q1 = hp[(size_t)e * 3 + 1];
    unsigned q2 = hp[(size_t)e * 3 + 2];
    uint4 p = *(const uint4*)(Yus + (size_t)src * 256 + d * 8);
    float m = bf16hi(p.z);                       // k5 = bias-matrix term
    m = fmaf(bf16lo(q0), bf16lo(p.x), m);
    m = fmaf(bf16hi(q0), bf16hi(p.x), m);
    m = fmaf(bf16lo(q1), bf16lo(p.y), m);
    m = fmaf(bf16hi(q1), bf16hi(p.y), m);
    m = fmaf(bf16lo(q2), bf16lo(p.z), m);
    atomicAdd(&obuf[(size_t)dst * 32 + d], m);
}

// ---- BN stats: per-channel sum & sumsq over nodes. ----
__global__ __launch_bounds__(256) void bn_reduce(
    const float* __restrict__ obuf, float* __restrict__ stats)
{
    __shared__ float ls[256];
    __shared__ float lq[256];
    int t = threadIdx.x;
    int c = t & 31, row = t >> 5;
    float s = 0.f, q = 0.f;
    for (int n = blockIdx.x * 8 + row; n < kN; n += gridDim.x * 8) {
        float v = obuf[(size_t)n * 32 + c];
        s += v; q += v * v;
    }
    ls[t] = s; lq[t] = q;
    __syncthreads();
    if (t < 128) { ls[t] += ls[t + 128]; lq[t] += lq[t + 128]; }
    __syncthreads();
    if (t < 64) { ls[t] += ls[t + 64]; lq[t] += lq[t + 64]; }
    __syncthreads();
    if (t < 32) {
        atomicAdd(&stats[t], ls[t] + ls[t + 32]);
        atomicAdd(&stats[32 + t], lq[t] + lq[t + 32]);
    }
}

// ---- final BN + prediction dot -> vbuf; init out with pred_b. ----
__global__ __launch_bounds__(256) void bn_norm_final(
    const float* __restrict__ obuf, const float* __restrict__ stats,
    const float* __restrict__ g, const float* __restrict__ b,
    float* __restrict__ vbuf, const float* __restrict__ predW,
    float* __restrict__ out, const float* __restrict__ pred_b)
{
    int idx = blockIdx.x * 256 + threadIdx.x;
    if (idx < kG) out[idx] = pred_b[0];
    if (idx >= kN * 32) return;
    int c = idx & 31;
    float mu = stats[c] * (1.f / kN);
    float var = stats[32 + c] * (1.f / kN) - mu * mu;
    float inv = rsqrtf(var + kEps);
    float v = (obuf[idx] - mu) * inv * g[c] + b[c];
    float pv = v * predW[c];
    #pragma unroll
    for (int off = 16; off > 0; off >>= 1) pv += __shfl_down(pv, off, 32);
    if (c == 0) vbuf[idx >> 5] = pv;
}

// ---- segment readout over sorted batch ids. ----
__global__ __launch_bounds__(256) void seg_readout(
    const float* __restrict__ vbuf, const int* __restrict__ batch,
    float* __restrict__ out)
{
    __shared__ float ls[kG];
    int t = threadIdx.x;
    for (int i = t; i < kG; i += 256) ls[i] = 0.f;
    __syncthreads();
    int base = blockIdx.x * 2048 + t * 8;
    int cur = -1; float acc = 0.f;
    #pragma unroll
    for (int i = 0; i < 8; ++i) {
        int n = base + i;
        if (n >= kN) break;
        int gi = batch[n];
        float val = vbuf[n];
        if (gi != cur) {
            if (cur >= 0) atomicAdd(&ls[cur], acc);
            cur = gi; acc = val;
        } else acc += val;
    }
    if (cur >= 0) atomicAdd(&ls[cur], acc);
    __syncthreads();
    for (int i = t; i < kG; i += 256) {
        float s = ls[i];
        if (s != 0.f) atomicAdd(&out[i], s);
    }
}

} // namespace

extern "C" void kernel_launch(void* const* d_in, const int* in_sizes, int n_in,
                              void* d_out, int out_size, void* d_ws, size_t ws_size,
                              hipStream_t stream)
{
    const float* x      = (const float*)d_in[0];
    const int*   ei     = (const int*)d_in[1];
    const float* ea     = (const float*)d_in[2];
    const int*   batch  = (const int*)d_in[3];
    const float* lin_W  = (const float*)d_in[4];
    const float* lin_b  = (const float*)d_in[5];
    const float* mes_W1 = (const float*)d_in[6];
    const float* mes_b1 = (const float*)d_in[7];
    const float* mes_W2 = (const float*)d_in[8];
    const float* mes_b2 = (const float*)d_in[9];
    const float* root_W = (const float*)d_in[10];
    const float* conv_b = (const float*)d_in[11];
    const float* bn_g   = (const float*)d_in[12];
    const float* bn_b   = (const float*)d_in[13];
    const float* pred_W = (const float*)d_in[14];
    const float* pred_b = (const float*)d_in[15];
    float* out = (float*)d_out;

    // ws: stats[64] | h16[N*32 us] | obuf[N*32 f32] | Y[N*256 us] | hidpk[3*E*3 u32]
    // vbuf[N] overlays Y (dead after last edge_msg).
    char* wsb = (char*)d_ws;
    float* stats = (float*)wsb;
    unsigned short* h16 = (unsigned short*)(wsb + 256);
    float* obuf = (float*)(h16 + (size_t)kN * 32);
    unsigned short* Yus = (unsigned short*)(obuf + (size_t)kN * 32);
    unsigned* hidpk = (unsigned*)(Yus + (size_t)kN * 256);
    float* vbuf = (float*)Yus;

    init_h<<<(kN + 255) / 256, 1024, 0, stream>>>(x, lin_W, lin_b, h16);
    hid_pre<<<(kE + 255) / 256, 256, 0, stream>>>(ea, mes_W1, mes_b1, hidpk);

    for (int l = 0; l < 3; ++l) {
        y_root<<<(kN + 255) / 256, 1024, 0, stream>>>(
            h16, obuf, mes_W2 + (size_t)l * 5120, mes_b2 + (size_t)l * 1024,
            root_W + (size_t)l * 1024, conv_b + l * 32, stats,
            bn_g + (l ? (l - 1) * 32 : 0), bn_b + (l ? (l - 1) * 32 : 0),
            l == 0 ? 1 : 0, Yus);
        edge_msg<<<kE * 32 / 256, 256, 0, stream>>>(
            ei, hidpk + (size_t)l * kE * 3, Yus, obuf, stats);
        bn_reduce<<<512, 256, 0, stream>>>(obuf, stats);
    }

    bn_norm_final<<<(kN * 32 + 255) / 256, 256, 0, stream>>>(
        obuf, stats, bn_g + 64, bn_b + 64, vbuf, pred_W, out, pred_b);
    seg_readout<<<(kN + 2047) / 2048, 256, 0, stream>>>(vbuf, batch, out);
}